// Round 8
// baseline (69.934 us; speedup 1.0000x reference)
//
#include <hip/hip_runtime.h>
#include <hip/hip_fp16.h>
#include <math.h>

#define ALPHA 0.001f
#define GAMMA 0.01f
#define DD 784
#define TD 1568          // 2*D floats per template row
#define V8ROW 196        // v8h (8 halves) per coded row: 784 h2 = 196*4
#define MM 256
#define BB 1024
#define NCLS 10
#define ROWS_PB 8
#define TPW 4            // templates per wave
#define NBLK 1024        // 128 rowgroups x 8 tgroups

typedef _Float16 v2h __attribute__((ext_vector_type(2)));
typedef _Float16 v8h __attribute__((ext_vector_type(8)));
typedef __fp16 f16x2 __attribute__((ext_vector_type(2)));
union H8 { v8h v; v2h p[4]; };

static __device__ __forceinline__ v2h pkrtz(float a, float b) {
  f16x2 r = __builtin_amdgcn_cvt_pkrtz(a, b);
  return __builtin_bit_cast(v2h, r);
}

// ws layout (floats):
//   [0..255] partial min | [256..511] partial max | [512..767] scale[m]
//   [768] min | [769] 1/(max-min+1e-10)

__global__ __launch_bounds__(256) void k_minmax(const float* __restrict__ x,
                                                float* __restrict__ ws,
                                                int* __restrict__ out_bits) {
  const float4* x4 = (const float4*)x;
  const int n4 = BB * DD / 4;
  int tid = blockIdx.x * 256 + threadIdx.x;
  if (tid < BB * NCLS) out_bits[tid] = (int)0xFF800000;  // -inf each launch
  float mn = 1e30f, mx = -1e30f;
  for (int i = tid; i < n4; i += 256 * 256) {
    float4 v = x4[i];
    mn = fminf(mn, fminf(fminf(v.x, v.y), fminf(v.z, v.w)));
    mx = fmaxf(mx, fmaxf(fmaxf(v.x, v.y), fmaxf(v.z, v.w)));
  }
#pragma unroll
  for (int off = 32; off; off >>= 1) {
    mn = fminf(mn, __shfl_xor(mn, off, 64));
    mx = fmaxf(mx, __shfl_xor(mx, off, 64));
  }
  __shared__ float smn[4], smx[4];
  int lane = threadIdx.x & 63, wid = threadIdx.x >> 6;
  if (lane == 0) { smn[wid] = mn; smx[wid] = mx; }
  __syncthreads();
  if (threadIdx.x == 0) {
    mn = fminf(fminf(smn[0], smn[1]), fminf(smn[2], smn[3]));
    mx = fmaxf(fmaxf(smx[0], smx[1]), fmaxf(smx[2], smx[3]));
    ws[blockIdx.x] = mn;
    ws[256 + blockIdx.x] = mx;
  }
}

__global__ __launch_bounds__(256) void k_stats(float* __restrict__ ws) {
  int tid = threadIdx.x;
  float mn = ws[tid], mx = ws[256 + tid];
#pragma unroll
  for (int off = 32; off; off >>= 1) {
    mn = fminf(mn, __shfl_xor(mn, off, 64));
    mx = fmaxf(mx, __shfl_xor(mx, off, 64));
  }
  __shared__ float smn[4], smx[4];
  int lane = tid & 63, wid = tid >> 6;
  if (lane == 0) { smn[wid] = mn; smx[wid] = mx; }
  __syncthreads();
  if (tid == 0) {
    mn = fminf(fminf(smn[0], smn[1]), fminf(smn[2], smn[3]));
    mx = fmaxf(fmaxf(smx[0], smx[1]), fmaxf(smx[2], smx[3]));
    ws[768] = mn;
    ws[769] = 1.0f / (mx - mn + 1e-10f);
  }
}

__global__ __launch_bounds__(64) void k_denom(const float* __restrict__ T,
                                              const int* __restrict__ committed,
                                              const int* __restrict__ counts,
                                              float* __restrict__ scale_out) {
  int m = blockIdx.x;
  int lane = threadIdx.x;
  const float4* t4 = (const float4*)(T + m * TD);
  float s = 0.f;
  for (int i = lane; i < TD / 4; i += 64) {
    float4 v = t4[i];
    s += (v.x + v.y) + (v.z + v.w);
  }
#pragma unroll
  for (int off = 32; off; off >>= 1) s += __shfl_xor(s, off, 64);
  if (lane == 0) {
    float denom = ALPHA + s + GAMMA * (float)counts[m];
    scale_out[m] = committed[m] ? (1.0f / denom) : -1.0f;
  }
}

// ---- shared body for main + ablations -------------------------------------
// MODE 0 = real (writes out_bits); 1 = NOLDS (cv from regs, asm sink);
// 2 = NOGLB (templates from regs, asm sink).
template <int MODE>
__device__ __forceinline__ void main_body(const float* __restrict__ x,
                                          const float* __restrict__ T,
                                          const int* __restrict__ labels,
                                          const float* __restrict__ ws,
                                          int* __restrict__ out_bits) {
  __shared__ v8h coded8[ROWS_PB * V8ROW];   // 8*196*16 = 25088 B
  __shared__ int clsmax[ROWS_PB][NCLS];

  int tid = threadIdx.x;
  int lane = tid & 63, wid = tid >> 6;
  int rg = blockIdx.x >> 3;
  int tg = blockIdx.x & 7;          // bid%8 -> XCD affinity for templates
  int row0 = rg * ROWS_PB;
  int m0 = tg * 32 + wid * TPW;

  float fmn = ws[768], finv = ws[769];
  float scv[TPW];
  int lbv[TPW];
#pragma unroll
  for (int t = 0; t < TPW; ++t) { scv[t] = ws[512 + m0 + t]; lbv[t] = labels[m0 + t]; }

  if (tid < ROWS_PB * NCLS) clsmax[tid / NCLS][tid % NCLS] = (int)0xFF800000;

  // ---- phase 1: stage 8 coded rows as v8h (b128 writes, no padding) ----
  for (int idx = tid; idx < ROWS_PB * V8ROW; idx += 512) {
    int r = idx / V8ROW;
    int t = idx - r * V8ROW;        // 0..195
    const float4* x4r = (const float4*)(x + (size_t)(row0 + r) * DD);
    int i2 = (t < 98) ? (2 * t) : (2 * (t - 98));
    float4 a = x4r[i2], b = x4r[i2 + 1];
    float v0 = (a.x - fmn) * finv, v1 = (a.y - fmn) * finv;
    float v2 = (a.z - fmn) * finv, v3 = (a.w - fmn) * finv;
    float v4 = (b.x - fmn) * finv, v5 = (b.y - fmn) * finv;
    float v6 = (b.z - fmn) * finv, v7 = (b.w - fmn) * finv;
    if (t >= 98) {
      v0 = 1.f - v0; v1 = 1.f - v1; v2 = 1.f - v2; v3 = 1.f - v3;
      v4 = 1.f - v4; v5 = 1.f - v5; v6 = 1.f - v6; v7 = 1.f - v7;
    }
    H8 u;
    u.p[0] = pkrtz(v0, v1);
    u.p[1] = pkrtz(v2, v3);
    u.p[2] = pkrtz(v4, v5);
    u.p[3] = pkrtz(v6, v7);
    coded8[idx] = u.v;
  }
  __syncthreads();

  // ---- phase 2: q=0..2 full-wave, q=3 tail (lanes 0..3), b128 LDS reads ----
  float acc[TPW][ROWS_PB];
#pragma unroll
  for (int t = 0; t < TPW; ++t)
#pragma unroll
    for (int r = 0; r < ROWS_PB; ++r) acc[t][r] = 0.f;

  v2h ones; ones.x = (_Float16)1.f; ones.y = (_Float16)1.f;
  v2h hk = pkrtz(finv, finv);  // reg const for ablations

#pragma unroll
  for (int q = 0; q < 4; ++q) {
    if (q < 3 || lane < 4) {
      H8 tq[TPW];
#pragma unroll
      for (int t = 0; t < TPW; ++t) {
        if (MODE == 2) {
          tq[t].p[0] = hk; tq[t].p[1] = hk; tq[t].p[2] = hk; tq[t].p[3] = hk;
        } else {
          const float4* tp = (const float4*)(T + (size_t)(m0 + t) * TD + q * 512);
          float4 fa = tp[2 * lane], fb = tp[2 * lane + 1];
          tq[t].p[0] = pkrtz(fa.x, fa.y);
          tq[t].p[1] = pkrtz(fa.z, fa.w);
          tq[t].p[2] = pkrtz(fb.x, fb.y);
          tq[t].p[3] = pkrtz(fb.z, fb.w);
        }
      }
#pragma unroll
      for (int r = 0; r < ROWS_PB; ++r) {
        H8 cv;
        if (MODE == 1) {
          cv.p[0] = hk; cv.p[1] = hk; cv.p[2] = hk; cv.p[3] = hk;
        } else {
          cv.v = coded8[r * V8ROW + q * 64 + lane];
        }
#pragma unroll
        for (int t = 0; t < TPW; ++t) {
          v2h m0_ = __builtin_elementwise_min(cv.p[0], tq[t].p[0]);
          v2h m1_ = __builtin_elementwise_min(cv.p[1], tq[t].p[1]);
          v2h m2_ = __builtin_elementwise_min(cv.p[2], tq[t].p[2]);
          v2h m3_ = __builtin_elementwise_min(cv.p[3], tq[t].p[3]);
          acc[t][r] = __builtin_amdgcn_fdot2(m0_, ones, acc[t][r], false);
          acc[t][r] = __builtin_amdgcn_fdot2(m1_, ones, acc[t][r], false);
          acc[t][r] = __builtin_amdgcn_fdot2(m2_, ones, acc[t][r], false);
          acc[t][r] = __builtin_amdgcn_fdot2(m3_, ones, acc[t][r], false);
        }
      }
    }
  }

  // ---- reduce: 32 butterflies, scatter lane = t*8+r ----
#pragma unroll
  for (int t = 0; t < TPW; ++t)
#pragma unroll
    for (int r = 0; r < ROWS_PB; ++r) {
      float a = acc[t][r];
#pragma unroll
      for (int off = 32; off; off >>= 1) a += __shfl_xor(a, off, 64);
      acc[t][r] = a;
    }
  float vout = 0.f;
#pragma unroll
  for (int t = 0; t < TPW; ++t)
#pragma unroll
    for (int r = 0; r < ROWS_PB; ++r)
      if (lane == t * 8 + r) vout = acc[t][r];

  if (MODE != 0) {
    asm volatile("" :: "v"(vout));   // keep live without output writes
    return;
  }

  float sc = -1.f; int lb = 0;
#pragma unroll
  for (int t = 0; t < TPW; ++t)
    if ((lane >> 3) == t) { sc = scv[t]; lb = lbv[t]; }
  if (lane < 32 && sc > 0.f)
    atomicMax(&clsmax[lane & 7][lb], __float_as_int(vout * sc));
  __syncthreads();

  if (tid < ROWS_PB * NCLS) {
    int rr = tid / NCLS, cc = tid - rr * NCLS;
    int bits = clsmax[rr][cc];
    if (bits != (int)0xFF800000)
      atomicMax(&out_bits[(row0 + rr) * NCLS + cc], bits);
  }
}

__global__ __launch_bounds__(512, 4) void k_main(const float* __restrict__ x,
                                                 const float* __restrict__ T,
                                                 const int* __restrict__ labels,
                                                 const float* __restrict__ ws,
                                                 int* __restrict__ out_bits) {
  main_body<0>(x, T, labels, ws, out_bits);
}
__global__ __launch_bounds__(512, 4) void k_abl_nolds(const float* __restrict__ x,
                                                      const float* __restrict__ T,
                                                      const int* __restrict__ labels,
                                                      const float* __restrict__ ws,
                                                      int* __restrict__ out_bits) {
  main_body<1>(x, T, labels, ws, out_bits);
}
__global__ __launch_bounds__(512, 4) void k_abl_noglb(const float* __restrict__ x,
                                                      const float* __restrict__ T,
                                                      const int* __restrict__ labels,
                                                      const float* __restrict__ ws,
                                                      int* __restrict__ out_bits) {
  main_body<2>(x, T, labels, ws, out_bits);
}

extern "C" void kernel_launch(void* const* d_in, const int* in_sizes, int n_in,
                              void* d_out, int out_size, void* d_ws, size_t ws_size,
                              hipStream_t stream) {
  const float* x = (const float*)d_in[0];
  const float* T = (const float*)d_in[1];
  const int* committed = (const int*)d_in[2];
  const int* labels = (const int*)d_in[3];
  const int* counts = (const int*)d_in[4];
  int* out_bits = (int*)d_out;
  float* ws = (float*)d_ws;

  k_minmax<<<dim3(256), dim3(256), 0, stream>>>(x, ws, out_bits);
  k_stats<<<dim3(1), dim3(256), 0, stream>>>(ws);
  k_denom<<<dim3(256), dim3(64), 0, stream>>>(T, committed, counts, ws + 512);
  k_main<<<dim3(NBLK), dim3(512), 0, stream>>>(x, T, labels, ws, out_bits);
  k_abl_nolds<<<dim3(NBLK), dim3(512), 0, stream>>>(x, T, labels, ws, out_bits);
  k_abl_noglb<<<dim3(NBLK), dim3(512), 0, stream>>>(x, T, labels, ws, out_bits);
}

// Round 10
// 45.226 us; speedup vs baseline: 1.5463x; 1.5463x over previous
//
#include <hip/hip_runtime.h>
#include <hip/hip_fp16.h>
#include <math.h>

#define ALPHA 0.001f
#define GAMMA 0.01f
#define DD 784
#define TD 1568          // 2*D floats per template row
#define V8ROW 196        // v8h (8 halves) per coded row: 784 h2 = 196*4
#define MM 256
#define BB 1024
#define NCLS 10
#define ROWS_PB 8
#define TPW 4            // templates per wave
#define NBLK 1024        // 128 rowgroups x 8 tgroups

typedef _Float16 v2h __attribute__((ext_vector_type(2)));
typedef _Float16 v8h __attribute__((ext_vector_type(8)));
typedef __fp16 f16x2 __attribute__((ext_vector_type(2)));
union H8 { v8h v; v2h p[4]; };

static __device__ __forceinline__ v2h pkrtz(float a, float b) {
  f16x2 r = __builtin_amdgcn_cvt_pkrtz(a, b);
  return __builtin_bit_cast(v2h, r);
}

// ---- DPP wave64 sum: VALU-pipe reduction (no DS traffic) ----
// ctrl/rmask must be literal constants -> template parameters.
template <int CTRL, int RMASK>
static __device__ __forceinline__ float dpp_add(float v) {
  int t = __builtin_amdgcn_update_dpp(0, __builtin_bit_cast(int, v),
                                      CTRL, RMASK, 0xf, false);
  return v + __builtin_bit_cast(float, t);
}
// row_shr 1,2,4,8 -> lane15 of each row16 holds row sum; row_bcast:15 (rows
// 1,3) then row_bcast:31 (rows 2,3) -> lane 63 = full 64-lane sum.
static __device__ __forceinline__ float wave_sum64_lane63(float v) {
  v = dpp_add<0x111, 0xf>(v);   // row_shr:1
  v = dpp_add<0x112, 0xf>(v);   // row_shr:2
  v = dpp_add<0x114, 0xf>(v);   // row_shr:4
  v = dpp_add<0x118, 0xf>(v);   // row_shr:8
  v = dpp_add<0x142, 0xa>(v);   // row_bcast:15 -> rows 1,3
  v = dpp_add<0x143, 0xc>(v);   // row_bcast:31 -> rows 2,3
  return v;
}

// ws layout (floats):
//   [0..255] partial min | [256..511] partial max | [512..767] scale[m]
//   [768] min | [769] 1/(max-min+1e-10)

__global__ __launch_bounds__(256) void k_minmax(const float* __restrict__ x,
                                                float* __restrict__ ws,
                                                int* __restrict__ out_bits) {
  const float4* x4 = (const float4*)x;
  const int n4 = BB * DD / 4;
  int tid = blockIdx.x * 256 + threadIdx.x;
  if (tid < BB * NCLS) out_bits[tid] = (int)0xFF800000;  // -inf each launch
  float mn = 1e30f, mx = -1e30f;
  for (int i = tid; i < n4; i += 256 * 256) {
    float4 v = x4[i];
    mn = fminf(mn, fminf(fminf(v.x, v.y), fminf(v.z, v.w)));
    mx = fmaxf(mx, fmaxf(fmaxf(v.x, v.y), fmaxf(v.z, v.w)));
  }
#pragma unroll
  for (int off = 32; off; off >>= 1) {
    mn = fminf(mn, __shfl_xor(mn, off, 64));
    mx = fmaxf(mx, __shfl_xor(mx, off, 64));
  }
  __shared__ float smn[4], smx[4];
  int lane = threadIdx.x & 63, wid = threadIdx.x >> 6;
  if (lane == 0) { smn[wid] = mn; smx[wid] = mx; }
  __syncthreads();
  if (threadIdx.x == 0) {
    mn = fminf(fminf(smn[0], smn[1]), fminf(smn[2], smn[3]));
    mx = fmaxf(fmaxf(smx[0], smx[1]), fmaxf(smx[2], smx[3]));
    ws[blockIdx.x] = mn;
    ws[256 + blockIdx.x] = mx;
  }
}

__global__ __launch_bounds__(256) void k_stats(float* __restrict__ ws) {
  int tid = threadIdx.x;
  float mn = ws[tid], mx = ws[256 + tid];
#pragma unroll
  for (int off = 32; off; off >>= 1) {
    mn = fminf(mn, __shfl_xor(mn, off, 64));
    mx = fmaxf(mx, __shfl_xor(mx, off, 64));
  }
  __shared__ float smn[4], smx[4];
  int lane = tid & 63, wid = tid >> 6;
  if (lane == 0) { smn[wid] = mn; smx[wid] = mx; }
  __syncthreads();
  if (tid == 0) {
    mn = fminf(fminf(smn[0], smn[1]), fminf(smn[2], smn[3]));
    mx = fmaxf(fmaxf(smx[0], smx[1]), fmaxf(smx[2], smx[3]));
    ws[768] = mn;
    ws[769] = 1.0f / (mx - mn + 1e-10f);
  }
}

__global__ __launch_bounds__(64) void k_denom(const float* __restrict__ T,
                                              const int* __restrict__ committed,
                                              const int* __restrict__ counts,
                                              float* __restrict__ scale_out) {
  int m = blockIdx.x;
  int lane = threadIdx.x;
  const float4* t4 = (const float4*)(T + m * TD);
  float s = 0.f;
  for (int i = lane; i < TD / 4; i += 64) {
    float4 v = t4[i];
    s += (v.x + v.y) + (v.z + v.w);
  }
#pragma unroll
  for (int off = 32; off; off >>= 1) s += __shfl_xor(s, off, 64);
  if (lane == 0) {
    float denom = ALPHA + s + GAMMA * (float)counts[m];
    scale_out[m] = committed[m] ? (1.0f / denom) : -1.0f;
  }
}

// grid: 1024 blocks = 128 rowgroups x 8 tgroups (bid&7 -> XCD affinity).
// 512 threads = 8 waves; wave owns TPW=4 templates; block stages 8 coded rows
// in LDS as v8h. Reductions are DPP (VALU pipe) -- the DS pipe only carries
// 32 b128 reads + ~3 staging writes + 1 atomic per wave.
__global__ __launch_bounds__(512, 4) void k_main(const float* __restrict__ x,
                                                 const float* __restrict__ T,
                                                 const int* __restrict__ labels,
                                                 const float* __restrict__ ws,
                                                 int* __restrict__ out_bits) {
  __shared__ v8h coded8[ROWS_PB * V8ROW];   // 8*196*16 = 25088 B
  __shared__ int clsmax[ROWS_PB][NCLS];

  int tid = threadIdx.x;
  int lane = tid & 63, wid = tid >> 6;
  int rg = blockIdx.x >> 3;
  int tg = blockIdx.x & 7;
  int row0 = rg * ROWS_PB;
  int m0 = tg * 32 + wid * TPW;

  float fmn = ws[768], finv = ws[769];
  float scv[TPW];
  int lbv[TPW];
#pragma unroll
  for (int t = 0; t < TPW; ++t) { scv[t] = ws[512 + m0 + t]; lbv[t] = labels[m0 + t]; }

  if (tid < ROWS_PB * NCLS) clsmax[tid / NCLS][tid % NCLS] = (int)0xFF800000;

  // ---- phase 1: stage 8 coded rows as v8h (b128 writes, no padding) ----
  for (int idx = tid; idx < ROWS_PB * V8ROW; idx += 512) {
    int r = idx / V8ROW;
    int t = idx - r * V8ROW;        // 0..195
    const float4* x4r = (const float4*)(x + (size_t)(row0 + r) * DD);
    int i2 = (t < 98) ? (2 * t) : (2 * (t - 98));
    float4 a = x4r[i2], b = x4r[i2 + 1];
    float v0 = (a.x - fmn) * finv, v1 = (a.y - fmn) * finv;
    float v2 = (a.z - fmn) * finv, v3 = (a.w - fmn) * finv;
    float v4 = (b.x - fmn) * finv, v5 = (b.y - fmn) * finv;
    float v6 = (b.z - fmn) * finv, v7 = (b.w - fmn) * finv;
    if (t >= 98) {
      v0 = 1.f - v0; v1 = 1.f - v1; v2 = 1.f - v2; v3 = 1.f - v3;
      v4 = 1.f - v4; v5 = 1.f - v5; v6 = 1.f - v6; v7 = 1.f - v7;
    }
    H8 u;
    u.p[0] = pkrtz(v0, v1);
    u.p[1] = pkrtz(v2, v3);
    u.p[2] = pkrtz(v4, v5);
    u.p[3] = pkrtz(v6, v7);
    coded8[idx] = u.v;
  }
  __syncthreads();

  // ---- phase 2: q=0..2 full-wave, q=3 tail (lanes 0..3), b128 LDS reads ----
  float acc[TPW][ROWS_PB];
#pragma unroll
  for (int t = 0; t < TPW; ++t)
#pragma unroll
    for (int r = 0; r < ROWS_PB; ++r) acc[t][r] = 0.f;

  v2h ones; ones.x = (_Float16)1.f; ones.y = (_Float16)1.f;

#pragma unroll
  for (int q = 0; q < 4; ++q) {
    if (q < 3 || lane < 4) {
      H8 tq[TPW];
#pragma unroll
      for (int t = 0; t < TPW; ++t) {
        const float4* tp = (const float4*)(T + (size_t)(m0 + t) * TD + q * 512);
        float4 fa = tp[2 * lane], fb = tp[2 * lane + 1];
        tq[t].p[0] = pkrtz(fa.x, fa.y);
        tq[t].p[1] = pkrtz(fa.z, fa.w);
        tq[t].p[2] = pkrtz(fb.x, fb.y);
        tq[t].p[3] = pkrtz(fb.z, fb.w);
      }
#pragma unroll
      for (int r = 0; r < ROWS_PB; ++r) {
        H8 cv;
        cv.v = coded8[r * V8ROW + q * 64 + lane];
#pragma unroll
        for (int t = 0; t < TPW; ++t) {
          v2h m0_ = __builtin_elementwise_min(cv.p[0], tq[t].p[0]);
          v2h m1_ = __builtin_elementwise_min(cv.p[1], tq[t].p[1]);
          v2h m2_ = __builtin_elementwise_min(cv.p[2], tq[t].p[2]);
          v2h m3_ = __builtin_elementwise_min(cv.p[3], tq[t].p[3]);
          acc[t][r] = __builtin_amdgcn_fdot2(m0_, ones, acc[t][r], false);
          acc[t][r] = __builtin_amdgcn_fdot2(m1_, ones, acc[t][r], false);
          acc[t][r] = __builtin_amdgcn_fdot2(m2_, ones, acc[t][r], false);
          acc[t][r] = __builtin_amdgcn_fdot2(m3_, ones, acc[t][r], false);
        }
      }
    }
  }

  // ---- reduce: 32 DPP sums (VALU) + readlane scatter (no DS traffic) ----
  float vout = 0.f;
#pragma unroll
  for (int t = 0; t < TPW; ++t)
#pragma unroll
    for (int r = 0; r < ROWS_PB; ++r) {
      float s = wave_sum64_lane63(acc[t][r]);
      float g = __builtin_bit_cast(float,
                  __builtin_amdgcn_readlane(__builtin_bit_cast(int, s), 63));
      if (lane == t * 8 + r) vout = g;
    }

  float sc = -1.f; int lb = 0;
#pragma unroll
  for (int t = 0; t < TPW; ++t)
    if ((lane >> 3) == t) { sc = scv[t]; lb = lbv[t]; }
  if (lane < 32 && sc > 0.f)
    atomicMax(&clsmax[lane & 7][lb], __float_as_int(vout * sc));
  __syncthreads();

  if (tid < ROWS_PB * NCLS) {
    int rr = tid / NCLS, cc = tid - rr * NCLS;
    int bits = clsmax[rr][cc];
    if (bits != (int)0xFF800000)
      atomicMax(&out_bits[(row0 + rr) * NCLS + cc], bits);
  }
}

extern "C" void kernel_launch(void* const* d_in, const int* in_sizes, int n_in,
                              void* d_out, int out_size, void* d_ws, size_t ws_size,
                              hipStream_t stream) {
  const float* x = (const float*)d_in[0];
  const float* T = (const float*)d_in[1];
  const int* committed = (const int*)d_in[2];
  const int* labels = (const int*)d_in[3];
  const int* counts = (const int*)d_in[4];
  int* out_bits = (int*)d_out;
  float* ws = (float*)d_ws;

  k_minmax<<<dim3(256), dim3(256), 0, stream>>>(x, ws, out_bits);
  k_stats<<<dim3(1), dim3(256), 0, stream>>>(ws);
  k_denom<<<dim3(256), dim3(64), 0, stream>>>(T, committed, counts, ws + 512);
  k_main<<<dim3(NBLK), dim3(512), 0, stream>>>(x, T, labels, ws, out_bits);
}